// Round 8
// baseline (231.253 us; speedup 1.0000x reference)
//
#include <hip/hip_runtime.h>
#include <hip/hip_bf16.h>
#include <math.h>

#define DIM 128
#define N_HEADS 8
#define HEAD_DIM 16
#define LDSW (DIM + 8)     // padded LDS row stride (ushorts) for W staging
#define NODE_B 256         // qv record: 64 dwords, dword d = q[2d],v16[2d],q[2d+1],v16[2d+1] (fp8)
#define MAXB 256           // max coarse buckets (N <= 65536)
#define EPB 4096           // edges per histogram/scatter chunk
#define VSCALE 16.0f       // v stored as fp8(16*v); undone in attn epilogue

typedef short bf16x8 __attribute__((ext_vector_type(8)));
typedef float f32x4 __attribute__((ext_vector_type(4)));
typedef float f32x2 __attribute__((ext_vector_type(2)));

// ---- bf16 helpers ----
__device__ __forceinline__ float bflo(unsigned int u) {
    union { unsigned int u; float f; } c; c.u = u << 16; return c.f;
}
__device__ __forceinline__ float bfhi(unsigned int u) {
    union { unsigned int u; float f; } c; c.u = u & 0xffff0000u; return c.f;
}
__device__ __forceinline__ unsigned short f2bf(float x) {
    union { float f; unsigned int u; } c; c.f = x;
    unsigned int r = (c.u + 0x7fffu + ((c.u >> 16) & 1u)) >> 16;  // RNE
    return (unsigned short)r;
}
__device__ __forceinline__ bf16x8 pack_bf16x8(float4 a, float4 b) {
    union { __hip_bfloat162 h2[4]; bf16x8 v; } u;
    u.h2[0] = __float22bfloat162_rn(make_float2(a.x, a.y));
    u.h2[1] = __float22bfloat162_rn(make_float2(a.z, a.w));
    u.h2[2] = __float22bfloat162_rn(make_float2(b.x, b.y));
    u.h2[3] = __float22bfloat162_rn(make_float2(b.z, b.w));
    return u.v;
}

// ---- fp8 e4m3 helpers ----
__device__ __forceinline__ unsigned char f2fp8(float x) {
#if __has_builtin(__builtin_amdgcn_cvt_pk_fp8_f32)
    return (unsigned char)(__builtin_amdgcn_cvt_pk_fp8_f32(x, x, 0, false) & 0xff);
#else
    union { float f; unsigned u; } c; c.f = x;
    unsigned s = (c.u >> 31) << 7;
    float a = fabsf(x);
    if (a < 0.000976562f) return (unsigned char)s;
    a = fminf(a, 448.f);
    union { float f; unsigned u; } d; d.f = a;
    int E = (int)((d.u >> 23) & 0xff) - 127;
    int e8 = E + 7;
    unsigned mant;
    if (e8 >= 1) {
        unsigned m = d.u & 0x7fffff;
        unsigned r = (m + 0x7ffff + ((m >> 20) & 1)) >> 20;
        if (r >= 8) { r = 0; e8++; }
        if (e8 > 15) { e8 = 15; r = 7; }
        mant = (unsigned)(e8 << 3) | r;
    } else {
        int r = (int)(a * 512.f + 0.5f);
        mant = (r > 7) ? 8u : (unsigned)r;
    }
    return (unsigned char)(s | mant);
#endif
}
// decode 2 fp8: HI=false -> bytes 0..1, HI=true -> bytes 2..3 (compile-time selector)
template <bool HI>
__device__ __forceinline__ f32x2 fp8x2_dec_sel(unsigned v) {
#if __has_builtin(__builtin_amdgcn_cvt_pk_f32_fp8)
    return __builtin_amdgcn_cvt_pk_f32_fp8((int)v, HI);
#else
    f32x2 r;
    unsigned sh = HI ? 16u : 0u;
#pragma unroll
    for (int i = 0; i < 2; ++i) {
        unsigned b = (v >> (sh + 8 * i)) & 0xff;
        unsigned s = b >> 7, e = (b >> 3) & 15, m = b & 7;
        float val;
        if (e) { union { unsigned u; float f; } c; c.u = ((e + 120) << 23) | (m << 20); val = c.f; }
        else val = (float)m * (1.f / 512.f);
        r[i] = s ? -val : val;
    }
    return r;
#endif
}

// ============ front kernel: 3 block roles, no inter-block dependencies ============
// role 0 (blocks [0, 2*nb))      : fused q+v projection -> interleaved fp8 records
// role 1 (blocks [2*nb, 3*nb))   : k projection -> bf16
// role 2 (blocks [3*nb, 3*nb+cb)): per-chunk coarse bucket histogram (non-atomic rows)
// Verified MFMA layouts (m89/m91/m97): A[m=lane&15][k=(lane>>4)*8+j]; C/D col=lane&15,
// row=(lane>>4)*4+reg.
__global__ __launch_bounds__(256, 2) void front_kernel(
    const float* __restrict__ h,
    const float* __restrict__ Wq, const float* __restrict__ Wk, const float* __restrict__ Wv,
    const float* __restrict__ bq, const float* __restrict__ bk, const float* __restrict__ bv,
    const int* __restrict__ dst, int* __restrict__ hist,
    unsigned char* __restrict__ qv, unsigned short* __restrict__ kb,
    int ntiles, int nb, int cblocks, int E) {
    __shared__ __align__(16) unsigned short wl2[2][DIM * LDSW];   // 69632 B
    const int bid = blockIdx.x;
    const int t = threadIdx.x;

    if (bid >= 3 * nb) {
        // ---- role 2: histogram chunk ----
        int* scnt = (int*)&wl2[0][0];
        const int chunk = bid - 3 * nb;
        if (chunk < cblocks) {
            scnt[t] = 0;
            __syncthreads();
            const int base = chunk * EPB;
            for (int j = t; j < EPB; j += 256) {
                int e = base + j;
                if (e < E) atomicAdd(&scnt[dst[e] >> 8], 1);
            }
            __syncthreads();
            hist[chunk * MAXB + t] = scnt[t];
        }
        return;
    }

    const int lane = t & 63;
    const int wid = t >> 6;
    const int ln15 = lane & 15;
    const int quad = lane >> 4;

    if (bid < 2 * nb) {
        // ---- role 0: fused q + v projection ----
        for (int i = t; i < DIM * DIM / 8; i += 256) {
            int r = i >> 4, c8 = i & 15;
            const float* wp = Wq + r * DIM + c8 * 8;
            *(bf16x8*)(&wl2[0][r * LDSW + c8 * 8]) =
                pack_bf16x8(*(const float4*)wp, *(const float4*)(wp + 4));
            const float* vp = Wv + r * DIM + c8 * 8;
            *(bf16x8*)(&wl2[1][r * LDSW + c8 * 8]) =
                pack_bf16x8(*(const float4*)vp, *(const float4*)(vp + 4));
        }
        __syncthreads();

        float bq_c[8], bv_c[8];
#pragma unroll
        for (int ct = 0; ct < 8; ++ct) {
            bq_c[ct] = bq[ct * 16 + ln15];
            bv_c[ct] = bv[ct * 16 + ln15];
        }

        const int wfirst = bid * 4 + wid;
        const int wstride = 2 * nb * 4;
        for (int rt = wfirst; rt < ntiles; rt += wstride) {
            const int r0 = rt * 16;
            const float* hrow = h + (size_t)(r0 + ln15) * DIM;
            bf16x8 afr[4];
#pragma unroll
            for (int kc = 0; kc < 4; ++kc) {
                float4 a0 = *(const float4*)(hrow + kc * 32 + quad * 8);
                float4 a1 = *(const float4*)(hrow + kc * 32 + quad * 8 + 4);
                afr[kc] = pack_bf16x8(a0, a1);
            }
#pragma unroll
            for (int ct = 0; ct < 8; ++ct) {
                f32x4 aq = (f32x4){0.f, 0.f, 0.f, 0.f};
                f32x4 av = (f32x4){0.f, 0.f, 0.f, 0.f};
#pragma unroll
                for (int kc = 0; kc < 4; ++kc) {
                    const int o = (ct * 16 + ln15) * LDSW + kc * 32 + quad * 8;
                    aq = __builtin_amdgcn_mfma_f32_16x16x32_bf16(afr[kc], *(const bf16x8*)&wl2[0][o], aq, 0, 0, 0);
                    av = __builtin_amdgcn_mfma_f32_16x16x32_bf16(afr[kc], *(const bf16x8*)&wl2[1][o], av, 0, 0, 0);
                }
                const int c = ct * 16 + ln15;
#pragma unroll
                for (int rg = 0; rg < 4; ++rg) {
                    const int row = r0 + quad * 4 + rg;
                    unsigned q8 = f2fp8(aq[rg] + bq_c[ct]);
                    unsigned v8 = f2fp8(VSCALE * (av[rg] + bv_c[ct]));
                    *(unsigned short*)(qv + (size_t)row * NODE_B + 2 * c) =
                        (unsigned short)(q8 | (v8 << 8));
                }
            }
        }
    } else {
        // ---- role 1: k projection ----
        for (int i = t; i < DIM * DIM / 8; i += 256) {
            int r = i >> 4, c8 = i & 15;
            const float* wp = Wk + r * DIM + c8 * 8;
            *(bf16x8*)(&wl2[0][r * LDSW + c8 * 8]) =
                pack_bf16x8(*(const float4*)wp, *(const float4*)(wp + 4));
        }
        __syncthreads();

        float bk_c[8];
#pragma unroll
        for (int ct = 0; ct < 8; ++ct) bk_c[ct] = bk[ct * 16 + ln15];

        const int wfirst = (bid - 2 * nb) * 4 + wid;
        const int wstride = nb * 4;
        for (int rt = wfirst; rt < ntiles; rt += wstride) {
            const int r0 = rt * 16;
            const float* hrow = h + (size_t)(r0 + ln15) * DIM;
            bf16x8 afr[4];
#pragma unroll
            for (int kc = 0; kc < 4; ++kc) {
                float4 a0 = *(const float4*)(hrow + kc * 32 + quad * 8);
                float4 a1 = *(const float4*)(hrow + kc * 32 + quad * 8 + 4);
                afr[kc] = pack_bf16x8(a0, a1);
            }
#pragma unroll
            for (int ct = 0; ct < 8; ++ct) {
                f32x4 acc = (f32x4){0.f, 0.f, 0.f, 0.f};
#pragma unroll
                for (int kc = 0; kc < 4; ++kc)
                    acc = __builtin_amdgcn_mfma_f32_16x16x32_bf16(
                        afr[kc], *(const bf16x8*)&wl2[0][(ct * 16 + ln15) * LDSW + kc * 32 + quad * 8],
                        acc, 0, 0, 0);
                const int c = ct * 16 + ln15;
#pragma unroll
                for (int rg = 0; rg < 4; ++rg) {
                    const int row = r0 + quad * 4 + rg;
                    kb[(size_t)row * DIM + c] = f2bf(acc[rg] + bk_c[ct]);
                }
            }
        }
    }
}

// ---------------- bucket scan: column-sum hist + scan -> boff/bcur; off[N]=E --------
__global__ __launch_bounds__(256) void bucket_scan_kernel(
    const int* __restrict__ hist, int nrows,
    int* __restrict__ boff, int* __restrict__ bcur,
    int* __restrict__ off, int nb, int n, int E) {
    __shared__ int buf[256];
    const int t = threadIdx.x;
    int v = 0;
    int j = 0;
    for (; j + 4 <= nrows; j += 4)
        v += hist[j * MAXB + t] + hist[(j + 1) * MAXB + t] +
             hist[(j + 2) * MAXB + t] + hist[(j + 3) * MAXB + t];
    for (; j < nrows; ++j) v += hist[j * MAXB + t];
    buf[t] = v;
    __syncthreads();
    for (int o = 1; o < 256; o <<= 1) {
        int u = (t >= o) ? buf[t - o] : 0;
        __syncthreads();
        buf[t] += u;
        __syncthreads();
    }
    if (t < nb) {
        int excl = buf[t] - v;
        boff[t] = excl;
        bcur[t] = excl;
    }
    if (t == 0) { boff[nb] = E; off[n] = E; }
}

// ---------------- bucket scatter: LDS multi-split, run-coalesced writes -------------
// packed edge: src(16) | dstLocal(8)<<16 | bucket(8)<<24
__global__ __launch_bounds__(256) void bucket_scatter_kernel(
    const int* __restrict__ src, const int* __restrict__ dst,
    int* __restrict__ bcur, unsigned int* __restrict__ pairs, int nb, int E) {
    __shared__ int cnt[MAXB];
    __shared__ int lbase[MAXB];
    __shared__ int gbase[MAXB];
    __shared__ int cur[MAXB];
    __shared__ unsigned int lbuf[EPB];
    const int t = threadIdx.x;
    const int base = blockIdx.x * EPB;
    const int valid = min(EPB, E - base);

    cnt[t] = 0;
    __syncthreads();
    for (int j = t; j < valid; j += 256) atomicAdd(&cnt[dst[base + j] >> 8], 1);
    __syncthreads();
    int v = cnt[t];
    lbase[t] = v;
    __syncthreads();
    for (int o = 1; o < 256; o <<= 1) {
        int u = (t >= o) ? lbase[t - o] : 0;
        __syncthreads();
        lbase[t] += u;
        __syncthreads();
    }
    int incl = lbase[t];
    __syncthreads();
    lbase[t] = incl - v;                 // exclusive
    if (t < nb) gbase[t] = v ? atomicAdd(&bcur[t], v) : 0;
    cur[t] = 0;
    __syncthreads();
    for (int j = t; j < valid; j += 256) {
        int d = dst[base + j];
        int bk = d >> 8;
        int r = atomicAdd(&cur[bk], 1);
        lbuf[lbase[bk] + r] = (unsigned)(src[base + j] & 0xffff) |
                              ((unsigned)(d & 255) << 16) | ((unsigned)bk << 24);
    }
    __syncthreads();
    for (int j = t; j < valid; j += 256) {
        unsigned int pv = lbuf[j];
        int bk = pv >> 24;
        pairs[gbase[bk] + (j - lbase[bk])] = pv;
    }
}

// ---------------- bucket finalize: per-bucket CSR (off) + ssrc placement ------------
__global__ __launch_bounds__(256) void bucket_finalize_kernel(
    const unsigned int* __restrict__ pairs, const int* __restrict__ boff,
    int* __restrict__ off, int* __restrict__ ssrc, int n) {
    __shared__ int deg[256];
    __shared__ int sbuf[256];
    __shared__ int cur[256];
    const int b = blockIdx.x;
    const int t = threadIdx.x;
    const int start = boff[b], end = boff[b + 1];

    deg[t] = 0;
    __syncthreads();
    for (int j = start + t; j < end; j += 256) atomicAdd(&deg[(pairs[j] >> 16) & 255], 1);
    __syncthreads();
    int v = deg[t];
    sbuf[t] = v;
    __syncthreads();
    for (int o = 1; o < 256; o <<= 1) {
        int u = (t >= o) ? sbuf[t - o] : 0;
        __syncthreads();
        sbuf[t] += u;
        __syncthreads();
    }
    int node_off = start + sbuf[t] - v;   // global CSR offset of node b*256+t
    cur[t] = node_off;
    int nd = b * 256 + t;
    if (nd < n) off[nd] = node_off;
    __syncthreads();
    for (int j = start + t; j < end; j += 256) {
        unsigned int pv = pairs[j];
        int p = atomicAdd(&cur[(pv >> 16) & 255], 1);
        ssrc[p] = (int)(pv & 0xffff);
    }
}

// ---------------- attention: 1 wave/node, dim-parallel, ONE dword gather per edge ---
// Record dword d = (q[2d], v16[2d], q[2d+1], v16[2d+1]) fp8. dec<false> -> (q_e, v_e),
// dec<true> -> (q_o, v_o). readlane -> SGPR base; 8/4/1 edge groups for MLP + short tail.
// No max-shift: scores ~N(0,0.05^2) by construction, exp cannot overflow.
__global__ __launch_bounds__(256) void attn_kernel(const unsigned char* __restrict__ qv,
                                                   const unsigned short* __restrict__ kb,
                                                   const int* __restrict__ off,
                                                   const int* __restrict__ ssrc,
                                                   unsigned short* __restrict__ aggb, int n) {
    const int lane = threadIdx.x & 63;
    const int node = blockIdx.x * 4 + (threadIdx.x >> 6);
    if (node >= n) return;

    unsigned int kraw = ((const unsigned int*)(kb + (size_t)node * DIM))[lane];
    const float k0 = bflo(kraw), k1 = bfhi(kraw);
    const int e0 = off[node], e1 = off[node + 1];

    float l = 0.f, a0 = 0.f, a1 = 0.f;

    for (int base = e0; base < e1; base += 64) {
        const int cnt = min(64, e1 - base);
        int s_all = (base + lane < e1) ? ssrc[base + lane] : 0;

        int j = 0;
        for (; j + 8 <= cnt; j += 8) {
            unsigned int w8[8];
#pragma unroll
            for (int u = 0; u < 8; ++u) {
                int s = __builtin_amdgcn_readlane(s_all, j + u);   // SGPR base
                w8[u] = *(const unsigned int*)(qv + (size_t)(unsigned)s * NODE_B + 4 * lane);
            }
            float p[8], v0[8], v1[8];
#pragma unroll
            for (int u = 0; u < 8; ++u) {
                f32x2 d0 = fp8x2_dec_sel<false>(w8[u]);   // (q_even, v_even)
                f32x2 d1 = fp8x2_dec_sel<true>(w8[u]);    // (q_odd,  v_odd)
                p[u] = fmaf(k0, d0[0], k1 * d1[0]);
                v0[u] = d0[1];
                v1[u] = d1[1];
            }
#pragma unroll
            for (int u = 0; u < 8; ++u) p[u] += __shfl_xor(p[u], 4, 8);
#pragma unroll
            for (int u = 0; u < 8; ++u) p[u] += __shfl_xor(p[u], 2, 8);
#pragma unroll
            for (int u = 0; u < 8; ++u) p[u] += __shfl_xor(p[u], 1, 8);
#pragma unroll
            for (int u = 0; u < 8; ++u) {
                float w = __expf(p[u] * 0.25f);
                l += w;
                a0 = fmaf(w, v0[u], a0);
                a1 = fmaf(w, v1[u], a1);
            }
        }
        for (; j + 4 <= cnt; j += 4) {
            unsigned int w4[4];
#pragma unroll
            for (int u = 0; u < 4; ++u) {
                int s = __builtin_amdgcn_readlane(s_all, j + u);
                w4[u] = *(const unsigned int*)(qv + (size_t)(unsigned)s * NODE_B + 4 * lane);
            }
            float p[4], v0[4], v1[4];
#pragma unroll
            for (int u = 0; u < 4; ++u) {
                f32x2 d0 = fp8x2_dec_sel<false>(w4[u]);
                f32x2 d1 = fp8x2_dec_sel<true>(w4[u]);
                p[u] = fmaf(k0, d0[0], k1 * d1[0]);
                v0[u] = d0[1];
                v1[u] = d1[1];
            }
#pragma unroll
            for (int u = 0; u < 4; ++u) p[u] += __shfl_xor(p[u], 4, 8);
#pragma unroll
            for (int u = 0; u < 4; ++u) p[u] += __shfl_xor(p[u], 2, 8);
#pragma unroll
            for (int u = 0; u < 4; ++u) p[u] += __shfl_xor(p[u], 1, 8);
#pragma unroll
            for (int u = 0; u < 4; ++u) {
                float w = __expf(p[u] * 0.25f);
                l += w;
                a0 = fmaf(w, v0[u], a0);
                a1 = fmaf(w, v1[u], a1);
            }
        }
        for (; j < cnt; ++j) {
            int s = __builtin_amdgcn_readlane(s_all, j);
            unsigned int w4 = *(const unsigned int*)(qv + (size_t)(unsigned)s * NODE_B + 4 * lane);
            f32x2 d0 = fp8x2_dec_sel<false>(w4);
            f32x2 d1 = fp8x2_dec_sel<true>(w4);
            float p = fmaf(k0, d0[0], k1 * d1[0]);
            p += __shfl_xor(p, 4, 8);
            p += __shfl_xor(p, 2, 8);
            p += __shfl_xor(p, 1, 8);
            float w = __expf(p * 0.25f);
            l += w;
            a0 = fmaf(w, d0[1], a0);
            a1 = fmaf(w, d1[1], a1);
        }
    }

    unsigned int o = 0;
    if (e1 > e0) {
        float rl = 1.f / (l * VSCALE);   // undo the v fp8 pre-scale
        o = (unsigned int)f2bf(a0 * rl) | ((unsigned int)f2bf(a1 * rl) << 16);
    }
    ((unsigned int*)(aggb + (size_t)node * DIM))[lane] = o;
}

// ---------------- output projection via MFMA: out = aggb @ Wo.T + bo (fp32 out) ----
__global__ __launch_bounds__(256, 2) void proj_o_mfma_kernel(
    const unsigned short* __restrict__ aggb,
    const float* __restrict__ Wo,
    const float* __restrict__ bo,
    float* __restrict__ out,
    int ntiles, int nwaves) {
    __shared__ __align__(16) unsigned short wl[DIM * LDSW];
    for (int i = threadIdx.x; i < DIM * DIM / 8; i += 256) {
        int r = i >> 4, c8 = i & 15;
        const float* wp = Wo + r * DIM + c8 * 8;
        *(bf16x8*)(wl + r * LDSW + c8 * 8) =
            pack_bf16x8(*(const float4*)wp, *(const float4*)(wp + 4));
    }
    __syncthreads();

    const int lane = threadIdx.x & 63;
    const int wave = blockIdx.x * 4 + (threadIdx.x >> 6);
    const int ln15 = lane & 15;
    const int quad = lane >> 4;

    float bias_c[8];
#pragma unroll
    for (int ct = 0; ct < 8; ++ct) bias_c[ct] = bo[ct * 16 + ln15];

    for (int rt = wave; rt < ntiles; rt += nwaves) {
        const int r0 = rt * 16;
        bf16x8 afr[4];
#pragma unroll
        for (int kc = 0; kc < 4; ++kc)
            afr[kc] = *(const bf16x8*)(aggb + (size_t)(r0 + ln15) * DIM + kc * 32 + quad * 8);
#pragma unroll
        for (int ct = 0; ct < 8; ++ct) {
            f32x4 acc = (f32x4){0.f, 0.f, 0.f, 0.f};
#pragma unroll
            for (int kc = 0; kc < 4; ++kc)
                acc = __builtin_amdgcn_mfma_f32_16x16x32_bf16(
                    afr[kc], *(const bf16x8*)(wl + (ct * 16 + ln15) * LDSW + kc * 32 + quad * 8),
                    acc, 0, 0, 0);
            const int c = ct * 16 + ln15;
#pragma unroll
            for (int rg = 0; rg < 4; ++rg) {
                const int row = r0 + quad * 4 + rg;
                out[(size_t)row * DIM + c] = acc[rg] + bias_c[ct];
            }
        }
    }
}

// ---------------- launch ----------------
extern "C" void kernel_launch(void* const* d_in, const int* in_sizes, int n_in,
                              void* d_out, int out_size, void* d_ws, size_t ws_size,
                              hipStream_t stream) {
    const float* h   = (const float*)d_in[0];
    const int*   src = (const int*)d_in[1];
    const int*   dst = (const int*)d_in[2];
    const float* Wq  = (const float*)d_in[3];
    const float* bq  = (const float*)d_in[4];
    const float* Wk  = (const float*)d_in[5];
    const float* bk  = (const float*)d_in[6];
    const float* Wv  = (const float*)d_in[7];
    const float* bv  = (const float*)d_in[8];
    const float* Wo  = (const float*)d_in[9];
    const float* bo  = (const float*)d_in[10];
    float* out = (float*)d_out;

    const int N = in_sizes[0] / DIM;   // 50000
    const int E = in_sizes[1];         // 800000
    const int NB = (N + 255) / 256;    // 196 coarse buckets
    const int cblocks = (E + EPB - 1) / EPB;  // 196
    const int ntiles = (N + 15) / 16;  // 3125

    // workspace layout (16B-aligned chunks)
    unsigned char*  qvb  = (unsigned char*)d_ws;                         // N*256
    unsigned short* kbuf = (unsigned short*)(qvb + (size_t)N * NODE_B);  // N*DIM bf16
    unsigned short* aggb = kbuf + (size_t)N * DIM;                       // N*DIM bf16
    int* off    = (int*)(aggb + (size_t)N * DIM);                        // N+1
    int* ssrc   = off + ((N + 1 + 3) & ~3);                              // E
    unsigned int* pairs = (unsigned int*)(ssrc + E);                     // E
    int* hist   = (int*)(pairs + E);                                     // cblocks*MAXB
    int* boff   = hist + cblocks * MAXB;                                 // MAXB+1
    int* bcur   = boff + MAXB + 4;                                       // MAXB

    // front: fused q+v (2*nb blocks) + k (nb blocks) + histogram (cblocks blocks)
    const int nb = 196;
    front_kernel<<<3 * nb + cblocks, 256, 0, stream>>>(
        h, Wq, Wk, Wv, bq, bk, bv, dst, hist, qvb, kbuf, ntiles, nb, cblocks, E);

    // bucket-sort CSR build
    bucket_scan_kernel<<<1, 256, 0, stream>>>(hist, cblocks, boff, bcur, off, NB, N, E);
    bucket_scatter_kernel<<<cblocks, 256, 0, stream>>>(src, dst, bcur, pairs, NB, E);
    bucket_finalize_kernel<<<NB, 256, 0, stream>>>(pairs, boff, off, ssrc, N);

    // attention aggregation (1 wave/node) -> bf16 agg
    attn_kernel<<<(N + 3) / 4, 256, 0, stream>>>(qvb, kbuf, off, ssrc, aggb, N);

    // output projection (MFMA, fp32 out)
    proj_o_mfma_kernel<<<nb, 256, 0, stream>>>(aggb, Wo, bo, out, ntiles, nb * 4);
}

// Round 9
// 208.819 us; speedup vs baseline: 1.1074x; 1.1074x over previous
//
#include <hip/hip_runtime.h>
#include <hip/hip_bf16.h>
#include <math.h>

#define DIM 128
#define N_HEADS 8
#define HEAD_DIM 16
#define LDSW (DIM + 8)     // padded LDS row stride (ushorts) for W staging
#define NODE_B 256         // qv record: 64 dwords, dword d = q[2d],v16[2d],q[2d+1],v16[2d+1] (fp8)
#define MAXB 256           // max coarse buckets (N <= 65536)
#define EPB 4096           // edges per histogram/scatter chunk
#define VSCALE 16.0f       // v stored as fp8(16*v); undone in attn epilogue

typedef short bf16x8 __attribute__((ext_vector_type(8)));
typedef float f32x4 __attribute__((ext_vector_type(4)));
typedef float f32x2 __attribute__((ext_vector_type(2)));

// ---- bf16 helpers ----
__device__ __forceinline__ float bflo(unsigned int u) {
    union { unsigned int u; float f; } c; c.u = u << 16; return c.f;
}
__device__ __forceinline__ float bfhi(unsigned int u) {
    union { unsigned int u; float f; } c; c.u = u & 0xffff0000u; return c.f;
}
__device__ __forceinline__ unsigned short f2bf(float x) {
    union { float f; unsigned int u; } c; c.f = x;
    unsigned int r = (c.u + 0x7fffu + ((c.u >> 16) & 1u)) >> 16;  // RNE
    return (unsigned short)r;
}
__device__ __forceinline__ bf16x8 pack_bf16x8(float4 a, float4 b) {
    union { __hip_bfloat162 h2[4]; bf16x8 v; } u;
    u.h2[0] = __float22bfloat162_rn(make_float2(a.x, a.y));
    u.h2[1] = __float22bfloat162_rn(make_float2(a.z, a.w));
    u.h2[2] = __float22bfloat162_rn(make_float2(b.x, b.y));
    u.h2[3] = __float22bfloat162_rn(make_float2(b.z, b.w));
    return u.v;
}

// ---- fp8 e4m3 helpers ----
__device__ __forceinline__ unsigned char f2fp8(float x) {
#if __has_builtin(__builtin_amdgcn_cvt_pk_fp8_f32)
    return (unsigned char)(__builtin_amdgcn_cvt_pk_fp8_f32(x, x, 0, false) & 0xff);
#else
    union { float f; unsigned u; } c; c.f = x;
    unsigned s = (c.u >> 31) << 7;
    float a = fabsf(x);
    if (a < 0.000976562f) return (unsigned char)s;
    a = fminf(a, 448.f);
    union { float f; unsigned u; } d; d.f = a;
    int E = (int)((d.u >> 23) & 0xff) - 127;
    int e8 = E + 7;
    unsigned mant;
    if (e8 >= 1) {
        unsigned m = d.u & 0x7fffff;
        unsigned r = (m + 0x7ffff + ((m >> 20) & 1)) >> 20;
        if (r >= 8) { r = 0; e8++; }
        if (e8 > 15) { e8 = 15; r = 7; }
        mant = (unsigned)(e8 << 3) | r;
    } else {
        int r = (int)(a * 512.f + 0.5f);
        mant = (r > 7) ? 8u : (unsigned)r;
    }
    return (unsigned char)(s | mant);
#endif
}
// decode 2 fp8: HI=false -> bytes 0..1, HI=true -> bytes 2..3 (compile-time selector)
template <bool HI>
__device__ __forceinline__ f32x2 fp8x2_dec_sel(unsigned v) {
#if __has_builtin(__builtin_amdgcn_cvt_pk_f32_fp8)
    return __builtin_amdgcn_cvt_pk_f32_fp8((int)v, HI);
#else
    f32x2 r;
    unsigned sh = HI ? 16u : 0u;
#pragma unroll
    for (int i = 0; i < 2; ++i) {
        unsigned b = (v >> (sh + 8 * i)) & 0xff;
        unsigned s = b >> 7, e = (b >> 3) & 15, m = b & 7;
        float val;
        if (e) { union { unsigned u; float f; } c; c.u = ((e + 120) << 23) | (m << 20); val = c.f; }
        else val = (float)m * (1.f / 512.f);
        r[i] = s ? -val : val;
    }
    return r;
#endif
}

// ========== qkv kernel: 3 roles, single 34.8KB LDS buffer, B-frags in registers =====
// role 0 (blocks [0, nb))        : q+v projection, two phases re-staging the one buffer
// role 1 (blocks [nb, 2*nb))     : k projection -> bf16
// role 2 (blocks [2*nb, 2*nb+cb)): per-chunk coarse bucket histogram (non-atomic rows)
// Verified MFMA layouts (m89/m91/m97): A[m=lane&15][k=(lane>>4)*8+j]; C/D col=lane&15,
// row=(lane>>4)*4+reg. Record byte: q[c] at 2c, v[c] at 2c+1 (interleaved).
__global__ __launch_bounds__(256, 2) void qkv_kernel(
    const float* __restrict__ h,
    const float* __restrict__ Wq, const float* __restrict__ Wk, const float* __restrict__ Wv,
    const float* __restrict__ bq, const float* __restrict__ bk, const float* __restrict__ bv,
    const int* __restrict__ dst, int* __restrict__ hist,
    unsigned char* __restrict__ qv, unsigned short* __restrict__ kb,
    int ntiles, int nb, int cblocks, int E) {
    __shared__ __align__(16) unsigned short wl[DIM * LDSW];   // 34816 B
    const int bid = blockIdx.x;
    const int t = threadIdx.x;

    if (bid >= 2 * nb) {
        // ---- role 2: histogram chunk ----
        int* scnt = (int*)wl;
        const int chunk = bid - 2 * nb;
        if (chunk < cblocks) {
            scnt[t] = 0;
            __syncthreads();
            const int base = chunk * EPB;
            for (int j = t; j < EPB; j += 256) {
                int e = base + j;
                if (e < E) atomicAdd(&scnt[dst[e] >> 8], 1);
            }
            __syncthreads();
            hist[chunk * MAXB + t] = scnt[t];
        }
        return;
    }

    const int lane = t & 63;
    const int wid = t >> 6;
    const int ln15 = lane & 15;
    const int quad = lane >> 4;
    const bool isk = (bid >= nb);
    const int nph = isk ? 1 : 2;
    const int wfirst = (isk ? bid - nb : bid) * 4 + wid;
    const int wstride = nb * 4;

    for (int ph = 0; ph < nph; ++ph) {
        const float* W = isk ? Wk : (ph ? Wv : Wq);
        const float* bias = isk ? bk : (ph ? bv : bq);
        if (ph) __syncthreads();          // all readers done with previous staging
        for (int i = t; i < DIM * DIM / 8; i += 256) {
            int r = i >> 4, c8 = i & 15;
            const float* wp = W + r * DIM + c8 * 8;
            *(bf16x8*)(wl + r * LDSW + c8 * 8) =
                pack_bf16x8(*(const float4*)wp, *(const float4*)(wp + 4));
        }
        __syncthreads();

        // hoist B-fragments to registers once per phase (R5-proven: keeps MFMA loop
        // free of LDS reads; 128 VGPRs, still 2 blocks/CU)
        bf16x8 bfr[8][4];
#pragma unroll
        for (int ct = 0; ct < 8; ++ct)
#pragma unroll
            for (int kc = 0; kc < 4; ++kc)
                bfr[ct][kc] = *(const bf16x8*)(wl + (ct * 16 + ln15) * LDSW + kc * 32 + quad * 8);

        float bias_c[8];
#pragma unroll
        for (int ct = 0; ct < 8; ++ct) bias_c[ct] = bias[ct * 16 + ln15];

        for (int rt = wfirst; rt < ntiles; rt += wstride) {
            const int r0 = rt * 16;
            const float* hrow = h + (size_t)(r0 + ln15) * DIM;
            bf16x8 afr[4];
#pragma unroll
            for (int kc = 0; kc < 4; ++kc) {
                float4 a0 = *(const float4*)(hrow + kc * 32 + quad * 8);
                float4 a1 = *(const float4*)(hrow + kc * 32 + quad * 8 + 4);
                afr[kc] = pack_bf16x8(a0, a1);
            }

            f32x4 acc[8];
#pragma unroll
            for (int ct = 0; ct < 8; ++ct) {
                acc[ct] = (f32x4){0.f, 0.f, 0.f, 0.f};
#pragma unroll
                for (int kc = 0; kc < 4; ++kc)
                    acc[ct] = __builtin_amdgcn_mfma_f32_16x16x32_bf16(afr[kc], bfr[ct][kc], acc[ct], 0, 0, 0);
            }

            if (isk) {
#pragma unroll
                for (int ct = 0; ct < 8; ++ct) {
                    const int c = ct * 16 + ln15;
#pragma unroll
                    for (int rg = 0; rg < 4; ++rg) {
                        const int row = r0 + quad * 4 + rg;
                        kb[(size_t)row * DIM + c] = f2bf(acc[ct][rg] + bias_c[ct]);
                    }
                }
            } else if (ph == 0) {
#pragma unroll
                for (int ct = 0; ct < 8; ++ct) {
                    const int c = ct * 16 + ln15;
#pragma unroll
                    for (int rg = 0; rg < 4; ++rg) {
                        const int row = r0 + quad * 4 + rg;
                        qv[(size_t)row * NODE_B + 2 * c] = f2fp8(acc[ct][rg] + bias_c[ct]);
                    }
                }
            } else {
#pragma unroll
                for (int ct = 0; ct < 8; ++ct) {
                    const int c = ct * 16 + ln15;
#pragma unroll
                    for (int rg = 0; rg < 4; ++rg) {
                        const int row = r0 + quad * 4 + rg;
                        qv[(size_t)row * NODE_B + 2 * c + 1] =
                            f2fp8(VSCALE * (acc[ct][rg] + bias_c[ct]));
                    }
                }
            }
        }
    }
}

// ---------------- bucket scan: column-sum hist + scan -> boff/bcur; off[N]=E --------
__global__ __launch_bounds__(256) void bucket_scan_kernel(
    const int* __restrict__ hist, int nrows,
    int* __restrict__ boff, int* __restrict__ bcur,
    int* __restrict__ off, int nb, int n, int E) {
    __shared__ int buf[256];
    const int t = threadIdx.x;
    int v = 0;
    int j = 0;
    for (; j + 4 <= nrows; j += 4)
        v += hist[j * MAXB + t] + hist[(j + 1) * MAXB + t] +
             hist[(j + 2) * MAXB + t] + hist[(j + 3) * MAXB + t];
    for (; j < nrows; ++j) v += hist[j * MAXB + t];
    buf[t] = v;
    __syncthreads();
    for (int o = 1; o < 256; o <<= 1) {
        int u = (t >= o) ? buf[t - o] : 0;
        __syncthreads();
        buf[t] += u;
        __syncthreads();
    }
    if (t < nb) {
        int excl = buf[t] - v;
        boff[t] = excl;
        bcur[t] = excl;
    }
    if (t == 0) { boff[nb] = E; off[n] = E; }
}

// ---------------- bucket scatter: LDS multi-split, run-coalesced writes -------------
// packed edge: src(16) | dstLocal(8)<<16 | bucket(8)<<24
__global__ __launch_bounds__(256) void bucket_scatter_kernel(
    const int* __restrict__ src, const int* __restrict__ dst,
    int* __restrict__ bcur, unsigned int* __restrict__ pairs, int nb, int E) {
    __shared__ int cnt[MAXB];
    __shared__ int lbase[MAXB];
    __shared__ int gbase[MAXB];
    __shared__ int cur[MAXB];
    __shared__ unsigned int lbuf[EPB];
    const int t = threadIdx.x;
    const int base = blockIdx.x * EPB;
    const int valid = min(EPB, E - base);

    cnt[t] = 0;
    __syncthreads();
    for (int j = t; j < valid; j += 256) atomicAdd(&cnt[dst[base + j] >> 8], 1);
    __syncthreads();
    int v = cnt[t];
    lbase[t] = v;
    __syncthreads();
    for (int o = 1; o < 256; o <<= 1) {
        int u = (t >= o) ? lbase[t - o] : 0;
        __syncthreads();
        lbase[t] += u;
        __syncthreads();
    }
    int incl = lbase[t];
    __syncthreads();
    lbase[t] = incl - v;                 // exclusive
    if (t < nb) gbase[t] = v ? atomicAdd(&bcur[t], v) : 0;
    cur[t] = 0;
    __syncthreads();
    for (int j = t; j < valid; j += 256) {
        int d = dst[base + j];
        int bk = d >> 8;
        int r = atomicAdd(&cur[bk], 1);
        lbuf[lbase[bk] + r] = (unsigned)(src[base + j] & 0xffff) |
                              ((unsigned)(d & 255) << 16) | ((unsigned)bk << 24);
    }
    __syncthreads();
    for (int j = t; j < valid; j += 256) {
        unsigned int pv = lbuf[j];
        int bk = pv >> 24;
        pairs[gbase[bk] + (j - lbase[bk])] = pv;
    }
}

// ---------------- bucket finalize: per-bucket CSR (off) + ssrc placement ------------
__global__ __launch_bounds__(256) void bucket_finalize_kernel(
    const unsigned int* __restrict__ pairs, const int* __restrict__ boff,
    int* __restrict__ off, int* __restrict__ ssrc, int n) {
    __shared__ int deg[256];
    __shared__ int sbuf[256];
    __shared__ int cur[256];
    const int b = blockIdx.x;
    const int t = threadIdx.x;
    const int start = boff[b], end = boff[b + 1];

    deg[t] = 0;
    __syncthreads();
    for (int j = start + t; j < end; j += 256) atomicAdd(&deg[(pairs[j] >> 16) & 255], 1);
    __syncthreads();
    int v = deg[t];
    sbuf[t] = v;
    __syncthreads();
    for (int o = 1; o < 256; o <<= 1) {
        int u = (t >= o) ? sbuf[t - o] : 0;
        __syncthreads();
        sbuf[t] += u;
        __syncthreads();
    }
    int node_off = start + sbuf[t] - v;   // global CSR offset of node b*256+t
    cur[t] = node_off;
    int nd = b * 256 + t;
    if (nd < n) off[nd] = node_off;
    __syncthreads();
    for (int j = start + t; j < end; j += 256) {
        unsigned int pv = pairs[j];
        int p = atomicAdd(&cur[(pv >> 16) & 255], 1);
        ssrc[p] = (int)(pv & 0xffff);
    }
}

// ---------------- attention: 1 wave/node, dim-parallel, ONE dword gather per edge ---
// Record dword d = (q[2d], v16[2d], q[2d+1], v16[2d+1]) fp8. dec<false> -> (q_e, v_e),
// dec<true> -> (q_o, v_o). readlane -> SGPR base; 8/4/1 edge groups for MLP + short tail.
// No max-shift: scores ~N(0,0.05^2) by construction, exp cannot overflow.
__global__ __launch_bounds__(256) void attn_kernel(const unsigned char* __restrict__ qv,
                                                   const unsigned short* __restrict__ kb,
                                                   const int* __restrict__ off,
                                                   const int* __restrict__ ssrc,
                                                   unsigned short* __restrict__ aggb, int n) {
    const int lane = threadIdx.x & 63;
    const int node = blockIdx.x * 4 + (threadIdx.x >> 6);
    if (node >= n) return;

    unsigned int kraw = ((const unsigned int*)(kb + (size_t)node * DIM))[lane];
    const float k0 = bflo(kraw), k1 = bfhi(kraw);
    const int e0 = off[node], e1 = off[node + 1];

    float l = 0.f, a0 = 0.f, a1 = 0.f;

    for (int base = e0; base < e1; base += 64) {
        const int cnt = min(64, e1 - base);
        int s_all = (base + lane < e1) ? ssrc[base + lane] : 0;

        int j = 0;
        for (; j + 8 <= cnt; j += 8) {
            unsigned int w8[8];
#pragma unroll
            for (int u = 0; u < 8; ++u) {
                int s = __builtin_amdgcn_readlane(s_all, j + u);   // SGPR base
                w8[u] = *(const unsigned int*)(qv + (size_t)(unsigned)s * NODE_B + 4 * lane);
            }
            float p[8], v0[8], v1[8];
#pragma unroll
            for (int u = 0; u < 8; ++u) {
                f32x2 d0 = fp8x2_dec_sel<false>(w8[u]);   // (q_even, v_even)
                f32x2 d1 = fp8x2_dec_sel<true>(w8[u]);    // (q_odd,  v_odd)
                p[u] = fmaf(k0, d0[0], k1 * d1[0]);
                v0[u] = d0[1];
                v1[u] = d1[1];
            }
#pragma unroll
            for (int u = 0; u < 8; ++u) p[u] += __shfl_xor(p[u], 4, 8);
#pragma unroll
            for (int u = 0; u < 8; ++u) p[u] += __shfl_xor(p[u], 2, 8);
#pragma unroll
            for (int u = 0; u < 8; ++u) p[u] += __shfl_xor(p[u], 1, 8);
#pragma unroll
            for (int u = 0; u < 8; ++u) {
                float w = __expf(p[u] * 0.25f);
                l += w;
                a0 = fmaf(w, v0[u], a0);
                a1 = fmaf(w, v1[u], a1);
            }
        }
        for (; j + 4 <= cnt; j += 4) {
            unsigned int w4[4];
#pragma unroll
            for (int u = 0; u < 4; ++u) {
                int s = __builtin_amdgcn_readlane(s_all, j + u);
                w4[u] = *(const unsigned int*)(qv + (size_t)(unsigned)s * NODE_B + 4 * lane);
            }
            float p[4], v0[4], v1[4];
#pragma unroll
            for (int u = 0; u < 4; ++u) {
                f32x2 d0 = fp8x2_dec_sel<false>(w4[u]);
                f32x2 d1 = fp8x2_dec_sel<true>(w4[u]);
                p[u] = fmaf(k0, d0[0], k1 * d1[0]);
                v0[u] = d0[1];
                v1[u] = d1[1];
            }
#pragma unroll
            for (int u = 0; u < 4; ++u) p[u] += __shfl_xor(p[u], 4, 8);
#pragma unroll
            for (int u = 0; u < 4; ++u) p[u] += __shfl_xor(p[u], 2, 8);
#pragma unroll
            for (int u = 0; u < 4; ++u) p[u] += __shfl_xor(p[u], 1, 8);
#pragma unroll
            for (int u = 0; u < 4; ++u) {
                float w = __expf(p[u] * 0.25f);
                l += w;
                a0 = fmaf(w, v0[u], a0);
                a1 = fmaf(w, v1[u], a1);
            }
        }
        for (; j < cnt; ++j) {
            int s = __builtin_amdgcn_readlane(s_all, j);
            unsigned int w4 = *(const unsigned int*)(qv + (size_t)(unsigned)s * NODE_B + 4 * lane);
            f32x2 d0 = fp8x2_dec_sel<false>(w4);
            f32x2 d1 = fp8x2_dec_sel<true>(w4);
            float p = fmaf(k0, d0[0], k1 * d1[0]);
            p += __shfl_xor(p, 4, 8);
            p += __shfl_xor(p, 2, 8);
            p += __shfl_xor(p, 1, 8);
            float w = __expf(p * 0.25f);
            l += w;
            a0 = fmaf(w, d0[1], a0);
            a1 = fmaf(w, d1[1], a1);
        }
    }

    unsigned int o = 0;
    if (e1 > e0) {
        float rl = 1.f / (l * VSCALE);   // undo the v fp8 pre-scale
        o = (unsigned int)f2bf(a0 * rl) | ((unsigned int)f2bf(a1 * rl) << 16);
    }
    ((unsigned int*)(aggb + (size_t)node * DIM))[lane] = o;
}

// ---------------- output projection via MFMA: out = aggb @ Wo.T + bo (fp32 out) ----
__global__ __launch_bounds__(256, 2) void proj_o_mfma_kernel(
    const unsigned short* __restrict__ aggb,
    const float* __restrict__ Wo,
    const float* __restrict__ bo,
    float* __restrict__ out,
    int ntiles, int nwaves) {
    __shared__ __align__(16) unsigned short wl[DIM * LDSW];
    for (int i = threadIdx.x; i < DIM * DIM / 8; i += 256) {
        int r = i >> 4, c8 = i & 15;
        const float* wp = Wo + r * DIM + c8 * 8;
        *(bf16x8*)(wl + r * LDSW + c8 * 8) =
            pack_bf16x8(*(const float4*)wp, *(const float4*)(wp + 4));
    }
    __syncthreads();

    const int lane = threadIdx.x & 63;
    const int wave = blockIdx.x * 4 + (threadIdx.x >> 6);
    const int ln15 = lane & 15;
    const int quad = lane >> 4;

    bf16x8 bfr[8][4];
#pragma unroll
    for (int ct = 0; ct < 8; ++ct)
#pragma unroll
        for (int kc = 0; kc < 4; ++kc)
            bfr[ct][kc] = *(const bf16x8*)(wl + (ct * 16 + ln15) * LDSW + kc * 32 + quad * 8);

    float bias_c[8];
#pragma unroll
    for (int ct = 0; ct < 8; ++ct) bias_c[ct] = bo[ct * 16 + ln15];

    for (int rt = wave; rt < ntiles; rt += nwaves) {
        const int r0 = rt * 16;
        bf16x8 afr[4];
#pragma unroll
        for (int kc = 0; kc < 4; ++kc)
            afr[kc] = *(const bf16x8*)(aggb + (size_t)(r0 + ln15) * DIM + kc * 32 + quad * 8);

        f32x4 acc[8];
#pragma unroll
        for (int ct = 0; ct < 8; ++ct) {
            acc[ct] = (f32x4){0.f, 0.f, 0.f, 0.f};
#pragma unroll
            for (int kc = 0; kc < 4; ++kc)
                acc[ct] = __builtin_amdgcn_mfma_f32_16x16x32_bf16(afr[kc], bfr[ct][kc], acc[ct], 0, 0, 0);
        }

#pragma unroll
        for (int ct = 0; ct < 8; ++ct) {
            const int c = ct * 16 + ln15;
#pragma unroll
            for (int rg = 0; rg < 4; ++rg) {
                const int row = r0 + quad * 4 + rg;
                out[(size_t)row * DIM + c] = acc[ct][rg] + bias_c[ct];
            }
        }
    }
}

// ---------------- launch ----------------
extern "C" void kernel_launch(void* const* d_in, const int* in_sizes, int n_in,
                              void* d_out, int out_size, void* d_ws, size_t ws_size,
                              hipStream_t stream) {
    const float* h   = (const float*)d_in[0];
    const int*   src = (const int*)d_in[1];
    const int*   dst = (const int*)d_in[2];
    const float* Wq  = (const float*)d_in[3];
    const float* bq  = (const float*)d_in[4];
    const float* Wk  = (const float*)d_in[5];
    const float* bk  = (const float*)d_in[6];
    const float* Wv  = (const float*)d_in[7];
    const float* bv  = (const float*)d_in[8];
    const float* Wo  = (const float*)d_in[9];
    const float* bo  = (const float*)d_in[10];
    float* out = (float*)d_out;

    const int N = in_sizes[0] / DIM;   // 50000
    const int E = in_sizes[1];         // 800000
    const int NB = (N + 255) / 256;    // 196 coarse buckets
    const int cblocks = (E + EPB - 1) / EPB;  // 196
    const int ntiles = (N + 15) / 16;  // 3125

    // workspace layout (16B-aligned chunks)
    unsigned char*  qvb  = (unsigned char*)d_ws;                         // N*256
    unsigned short* kbuf = (unsigned short*)(qvb + (size_t)N * NODE_B);  // N*DIM bf16
    unsigned short* aggb = kbuf + (size_t)N * DIM;                       // N*DIM bf16
    int* off    = (int*)(aggb + (size_t)N * DIM);                        // N+1
    int* ssrc   = off + ((N + 1 + 3) & ~3);                              // E
    unsigned int* pairs = (unsigned int*)(ssrc + E);                     // E
    int* hist   = (int*)(pairs + E);                                     // cblocks*MAXB
    int* boff   = hist + cblocks * MAXB;                                 // MAXB+1
    int* bcur   = boff + MAXB + 4;                                       // MAXB

    // qkv + k + histogram in one launch (3 block roles, same LDS footprint)
    const int nb = 196;
    qkv_kernel<<<2 * nb + cblocks, 256, 0, stream>>>(
        h, Wq, Wk, Wv, bq, bk, bv, dst, hist, qvb, kbuf, ntiles, nb, cblocks, E);

    // bucket-sort CSR build
    bucket_scan_kernel<<<1, 256, 0, stream>>>(hist, cblocks, boff, bcur, off, NB, N, E);
    bucket_scatter_kernel<<<cblocks, 256, 0, stream>>>(src, dst, bcur, pairs, NB, E);
    bucket_finalize_kernel<<<NB, 256, 0, stream>>>(pairs, boff, off, ssrc, N);

    // attention aggregation (1 wave/node) -> bf16 agg
    attn_kernel<<<(N + 3) / 4, 256, 0, stream>>>(qvb, kbuf, off, ssrc, aggb, N);

    // output projection (MFMA, fp32 out)
    proj_o_mfma_kernel<<<nb, 256, 0, stream>>>(aggb, Wo, bo, out, ntiles, nb * 4);
}